// Round 4
// baseline (97.477 us; speedup 1.0000x reference)
//
#include <hip/hip_runtime.h>
#include <hip/hip_bf16.h>

// SelfAttention: B=2, S=4096, E=512, D=64, fp32 in/out.
// R4 = R1 (verified) + ONE change: key-split attention (grid.y=2) with
// cross-block merge. All arithmetic identical to the passing R1 kernel.

typedef float  f32x16 __attribute__((ext_vector_type(16)));
typedef short  v8bf   __attribute__((ext_vector_type(8)));
typedef int    v4i    __attribute__((ext_vector_type(4)));

#define MFMA32(a, b, c) __builtin_amdgcn_mfma_f32_32x32x16_bf16((a), (b), (c), 0, 0, 0)

union Frag { v4i i4; v8bf b8; unsigned u[4]; };

__device__ __forceinline__ unsigned short f2bf(float x) {  // RNE fp32->bf16
    unsigned u = __float_as_uint(x);
    return (unsigned short)((u + 0x7fffu + ((u >> 16) & 1u)) >> 16);
}
__device__ __forceinline__ float bf2f(unsigned short h) {
    return __uint_as_float(((unsigned)h) << 16);
}
__device__ __forceinline__ unsigned cvt_pk_bf16(float a, float b) {
    unsigned r;
    asm("v_cvt_pk_bf16_f32 %0, %1, %2" : "=v"(r) : "v"(a), "v"(b));
    return r;
}

// ---------------- split kernels: fp32 -> (hi, lo) bf16 ----------------

__global__ __launch_bounds__(256) void split_kernel(
    const float* __restrict__ src, unsigned short* __restrict__ hi,
    unsigned short* __restrict__ lo, int n4)
{
    int i = blockIdx.x * 256 + threadIdx.x;
    const int stride = gridDim.x * 256;
    for (; i < n4; i += stride) {
        float4 v = reinterpret_cast<const float4*>(src)[i];
        unsigned short h0 = f2bf(v.x), h1 = f2bf(v.y), h2 = f2bf(v.z), h3 = f2bf(v.w);
        unsigned short l0 = f2bf(v.x - bf2f(h0)), l1 = f2bf(v.y - bf2f(h1));
        unsigned short l2 = f2bf(v.z - bf2f(h2)), l3 = f2bf(v.w - bf2f(h3));
        reinterpret_cast<uint2*>(hi)[i] =
            make_uint2((unsigned)h0 | ((unsigned)h1 << 16), (unsigned)h2 | ((unsigned)h3 << 16));
        reinterpret_cast<uint2*>(lo)[i] =
            make_uint2((unsigned)l0 | ((unsigned)l1 << 16), (unsigned)l2 | ((unsigned)l3 << 16));
    }
}

// Pack Wq,Wk,Wv (each [64][512]) into W[192][512] hi/lo. 24576 float4s -> 96 blocks.
__global__ __launch_bounds__(256) void splitW_kernel(
    const float* __restrict__ wq, const float* __restrict__ wk, const float* __restrict__ wv,
    unsigned short* __restrict__ hi, unsigned short* __restrict__ lo)
{
    int i = blockIdx.x * 256 + threadIdx.x;  // exactly 24576 threads
    int e = i * 4;
    const float* src = (e < 32768) ? wq : (e < 65536) ? wk : wv;
    int off = e & 32767;
    float4 v = *reinterpret_cast<const float4*>(src + off);
    unsigned short h0 = f2bf(v.x), h1 = f2bf(v.y), h2 = f2bf(v.z), h3 = f2bf(v.w);
    unsigned short l0 = f2bf(v.x - bf2f(h0)), l1 = f2bf(v.y - bf2f(h1));
    unsigned short l2 = f2bf(v.z - bf2f(h2)), l3 = f2bf(v.w - bf2f(h3));
    reinterpret_cast<uint2*>(hi)[i] =
        make_uint2((unsigned)h0 | ((unsigned)h1 << 16), (unsigned)h2 | ((unsigned)h3 << 16));
    reinterpret_cast<uint2*>(lo)[i] =
        make_uint2((unsigned)l0 | ((unsigned)l1 << 16), (unsigned)l2 | ((unsigned)l3 << 16));
}

// ---------------- projection: C[8192][192] = X[8192][512] @ W^T ----------------
// grid = (256 row-tiles, 3 col-groups: 0=Q, 1=K, 2=V), 1 wave/block.

__global__ __launch_bounds__(64) void proj_kernel(
    const unsigned short* __restrict__ Xhi, const unsigned short* __restrict__ Xlo,
    const unsigned short* __restrict__ Whi, const unsigned short* __restrict__ Wlo,
    unsigned short* __restrict__ Qhi, unsigned short* __restrict__ Qlo,
    unsigned short* __restrict__ Khi, unsigned short* __restrict__ Klo,
    unsigned short* __restrict__ VT)
{
    __shared__ float t[32][33];
    const int l = threadIdx.x, h = l >> 5, r32 = l & 31;
    const int row0 = blockIdx.x * 32;
    const int g = blockIdx.y;

    f32x16 a0, a1;
#pragma unroll
    for (int r = 0; r < 16; ++r) { a0[r] = 0.f; a1[r] = 0.f; }

    for (int kc = 0; kc < 32; ++kc) {
        const int k0 = kc * 16 + 8 * h;
        Frag xh, xl, b0h, b1h;
        const int xo = (row0 + r32) * 512 + k0;
        const int w0 = (g * 64 + r32) * 512 + k0;
        const int w1 = w0 + 32 * 512;
        xh.i4  = *reinterpret_cast<const v4i*>(Xhi + xo);
        b0h.i4 = *reinterpret_cast<const v4i*>(Whi + w0);
        b1h.i4 = *reinterpret_cast<const v4i*>(Whi + w1);
        a0 = MFMA32(xh.b8, b0h.b8, a0);
        a1 = MFMA32(xh.b8, b1h.b8, a1);
        if (g < 2) {  // Q,K need the hi/lo cross terms
            Frag b0l, b1l;
            xl.i4  = *reinterpret_cast<const v4i*>(Xlo + xo);
            b0l.i4 = *reinterpret_cast<const v4i*>(Wlo + w0);
            b1l.i4 = *reinterpret_cast<const v4i*>(Wlo + w1);
            a0 = MFMA32(xh.b8, b0l.b8, a0);
            a0 = MFMA32(xl.b8, b0h.b8, a0);
            a1 = MFMA32(xh.b8, b1l.b8, a1);
            a1 = MFMA32(xl.b8, b1h.b8, a1);
        }
    }

    if (g == 2) {
        // V: C[row=s][col=v]; store VT[b][v][s] directly (4 consecutive s per reg-quad)
        const int b  = row0 >> 12;
        const int s0 = row0 & 4095;
#pragma unroll
        for (int ct = 0; ct < 2; ++ct) {
            const f32x16& a = ct ? a1 : a0;
            const int v = ct * 32 + r32;
#pragma unroll
            for (int u = 0; u < 4; ++u) {
                const int srow = s0 + 8 * u + 4 * h;
                unsigned p0 = (unsigned)f2bf(a[4 * u])     | ((unsigned)f2bf(a[4 * u + 1]) << 16);
                unsigned p1 = (unsigned)f2bf(a[4 * u + 2]) | ((unsigned)f2bf(a[4 * u + 3]) << 16);
                *reinterpret_cast<uint2*>(VT + (b * 64 + v) * 4096 + srow) = make_uint2(p0, p1);
            }
        }
    } else {
        unsigned short* Oh = g ? Khi : Qhi;
        unsigned short* Ol = g ? Klo : Qlo;
#pragma unroll
        for (int ct = 0; ct < 2; ++ct) {
            const f32x16& a = ct ? a1 : a0;
            __syncthreads();
#pragma unroll
            for (int u = 0; u < 16; ++u)
                t[(u & 3) + 8 * (u >> 2) + 4 * h][r32] = a[u];
            __syncthreads();
            unsigned wh[8], wl[8];
#pragma unroll
            for (int j = 0; j < 8; ++j) {
                float x0 = t[r32][16 * h + 2 * j];
                float x1 = t[r32][16 * h + 2 * j + 1];
                unsigned short h0 = f2bf(x0), h1 = f2bf(x1);
                unsigned short l0 = f2bf(x0 - bf2f(h0)), l1 = f2bf(x1 - bf2f(h1));
                wh[j] = (unsigned)h0 | ((unsigned)h1 << 16);
                wl[j] = (unsigned)l0 | ((unsigned)l1 << 16);
            }
            const int off = (row0 + r32) * 64 + ct * 32 + 16 * h;
            *reinterpret_cast<uint4*>(Oh + off)     = make_uint4(wh[0], wh[1], wh[2], wh[3]);
            *reinterpret_cast<uint4*>(Oh + off + 8) = make_uint4(wh[4], wh[5], wh[6], wh[7]);
            *reinterpret_cast<uint4*>(Ol + off)     = make_uint4(wl[0], wl[1], wl[2], wl[3]);
            *reinterpret_cast<uint4*>(Ol + off + 8) = make_uint4(wl[4], wl[5], wl[6], wl[7]);
        }
    }
}

// ---------------- flash attention (key-split halves) ----------------
// grid (256 q-tiles, 2 key-halves), block 512 (8 waves). Wave w: 256 keys of
// its half (8 iters x 32). All math identical to R1; epilogue writes
// unnormalized partial (O, m*, L) instead of the final output.

__global__ __launch_bounds__(512) void attn_kernel(
    const unsigned short* __restrict__ Qhi, const unsigned short* __restrict__ Qlo,
    const unsigned short* __restrict__ Khi, const unsigned short* __restrict__ Klo,
    const unsigned short* __restrict__ VT,
    float* __restrict__ Opart, float* __restrict__ ml)
{
    __shared__ float sO[8][32][68];
    __shared__ float sm[8][32];
    __shared__ float sl[8][32];

    const int tid = threadIdx.x;
    const int w = tid >> 6;
    const int l = tid & 63;
    const int h = l >> 5;
    const int q = l & 31;
    const int b  = blockIdx.x >> 7;
    const int q0 = (blockIdx.x & 127) * 32;
    const int half = blockIdx.y;

    // Q fragments (B-operand of swapped QK^T): Q[q][d], 4 d-chunks of 16
    Frag qh[4], ql[4];
#pragma unroll
    for (int dc = 0; dc < 4; ++dc) {
        const int o = (b * 4096 + q0 + q) * 64 + dc * 16 + 8 * h;
        qh[dc].i4 = *reinterpret_cast<const v4i*>(Qhi + o);
        ql[dc].i4 = *reinterpret_cast<const v4i*>(Qlo + o);
    }

    f32x16 o0, o1;
#pragma unroll
    for (int r = 0; r < 16; ++r) { o0[r] = 0.f; o1[r] = 0.f; }
    float m_run = -1e30f, l_run = 0.f;

    for (int it = 0; it < 8; ++it) {
        const int key0 = half * 2048 + (it * 8 + w) * 32;
        // --- scores: S[k][q] = sum_d K[k][d] Q[q][d], hi/lo split (3 MFMAs/chunk)
        f32x16 s;
#pragma unroll
        for (int r = 0; r < 16; ++r) s[r] = 0.f;
#pragma unroll
        for (int dc = 0; dc < 4; ++dc) {
            Frag kh, kl;
            const int ko = (b * 4096 + key0 + q) * 64 + dc * 16 + 8 * h;
            kh.i4 = *reinterpret_cast<const v4i*>(Khi + ko);
            kl.i4 = *reinterpret_cast<const v4i*>(Klo + ko);
            s = MFMA32(kh.b8, qh[dc].b8, s);
            s = MFMA32(kh.b8, ql[dc].b8, s);
            s = MFMA32(kl.b8, qh[dc].b8, s);
        }
        // --- online softmax (base 2). Quirk: logits = 8 * score.
        const float cc = 11.541560327111707f;  // 8 * log2(e)
        float s2[16];
        float mb = -1e30f;
#pragma unroll
        for (int r = 0; r < 16; ++r) { s2[r] = s[r] * cc; mb = fmaxf(mb, s2[r]); }
        mb = fmaxf(mb, __shfl_xor(mb, 32));
        const float m_new = fmaxf(m_run, mb);
        const float f = exp2f(m_run - m_new);
        float p[16];
        float ps = 0.f;
#pragma unroll
        for (int r = 0; r < 16; ++r) { p[r] = exp2f(s2[r] - m_new); ps += p[r]; }
        ps += __shfl_xor(ps, 32);
        l_run = l_run * f + ps;
        m_run = m_new;
#pragma unroll
        for (int r = 0; r < 16; ++r) { o0[r] *= f; o1[r] *= f; }

        // --- P (C layout, k = (r&3)+8*(r>>2)+4h) -> bf16 B-frags (k = 16c+8h+j)
        unsigned U[8];
#pragma unroll
        for (int g = 0; g < 4; ++g) {
            U[2 * g]     = cvt_pk_bf16(p[4 * g],     p[4 * g + 1]);
            U[2 * g + 1] = cvt_pk_bf16(p[4 * g + 2], p[4 * g + 3]);
        }
        unsigned t0 = h ? U[0] : U[2];
        unsigned t1 = h ? U[1] : U[3];
        unsigned t2 = h ? U[4] : U[6];
        unsigned t3 = h ? U[5] : U[7];
        unsigned r0 = __shfl_xor(t0, 32);
        unsigned r1 = __shfl_xor(t1, 32);
        unsigned r2 = __shfl_xor(t2, 32);
        unsigned r3 = __shfl_xor(t3, 32);
        Frag p0f, p1f;
        if (h == 0) {
            p0f.u[0] = U[0]; p0f.u[1] = U[1]; p0f.u[2] = r0; p0f.u[3] = r1;
            p1f.u[0] = U[4]; p1f.u[1] = U[5]; p1f.u[2] = r2; p1f.u[3] = r3;
        } else {
            p0f.u[0] = r0; p0f.u[1] = r1; p0f.u[2] = U[2]; p0f.u[3] = U[3];
            p1f.u[0] = r2; p1f.u[1] = r3; p1f.u[2] = U[6]; p1f.u[3] = U[7];
        }
        // --- PV: O^T[v][q] += V^T[v][k] P[k][q]
#pragma unroll
        for (int c = 0; c < 2; ++c) {
            const Frag& pf = c ? p1f : p0f;
#pragma unroll
            for (int vc = 0; vc < 2; ++vc) {
                Frag vf;
                const int vo = (b * 64 + vc * 32 + q) * 4096 + key0 + c * 16 + 8 * h;
                vf.i4 = *reinterpret_cast<const v4i*>(VT + vo);
                if (vc == 0) o0 = MFMA32(vf.b8, pf.b8, o0);
                else         o1 = MFMA32(vf.b8, pf.b8, o1);
            }
        }
    }

    // --- merge the 8 per-wave partials -> per-block partial (m*, L, unnorm O)
    if (h == 0) { sm[w][q] = m_run; sl[w][q] = l_run; }
#pragma unroll
    for (int vc = 0; vc < 2; ++vc) {
        const f32x16& a = vc ? o1 : o0;
#pragma unroll
        for (int u = 0; u < 4; ++u) {
            float4 v4 = make_float4(a[4 * u], a[4 * u + 1], a[4 * u + 2], a[4 * u + 3]);
            *reinterpret_cast<float4*>(&sO[w][q][vc * 32 + 8 * u + 4 * h]) = v4;
        }
    }
    __syncthreads();

    const int qq = tid >> 4;
    const int vb = (tid & 15) * 4;
    float mstar = sm[0][qq];
#pragma unroll
    for (int ww = 1; ww < 8; ++ww) mstar = fmaxf(mstar, sm[ww][qq]);
    float L = 0.f, acc0 = 0.f, acc1 = 0.f, acc2 = 0.f, acc3 = 0.f;
#pragma unroll
    for (int ww = 0; ww < 8; ++ww) {
        const float fw = exp2f(sm[ww][qq] - mstar);
        L += fw * sl[ww][qq];
        acc0 += fw * sO[ww][qq][vb + 0];
        acc1 += fw * sO[ww][qq][vb + 1];
        acc2 += fw * sO[ww][qq][vb + 2];
        acc3 += fw * sO[ww][qq][vb + 3];
    }
    const int row = b * 4096 + q0 + qq;
    *reinterpret_cast<float4*>(Opart + ((size_t)half * 8192 + row) * 64 + vb) =
        make_float4(acc0, acc1, acc2, acc3);
    if (vb == 0) {
        ml[((size_t)half * 8192 + row) * 2 + 0] = mstar;
        ml[((size_t)half * 8192 + row) * 2 + 1] = L;
    }
}

// ---------------- cross-block merge of the 2 key-halves ----------------
__global__ __launch_bounds__(256) void merge_kernel(
    const float* __restrict__ Opart, const float* __restrict__ ml, float* __restrict__ out)
{
    const int idx = blockIdx.x * 256 + threadIdx.x;  // 131072
    const int row = idx >> 4, vb = (idx & 15) * 4;
    const float m0 = ml[row * 2 + 0],            l0 = ml[row * 2 + 1];
    const float m1 = ml[(8192 + row) * 2 + 0],   l1 = ml[(8192 + row) * 2 + 1];
    const float ms = fmaxf(m0, m1);
    const float w0 = exp2f(m0 - ms), w1 = exp2f(m1 - ms);
    const float inv = 1.0f / (w0 * l0 + w1 * l1);
    float4 a = *reinterpret_cast<const float4*>(Opart + (size_t)row * 64 + vb);
    float4 c = *reinterpret_cast<const float4*>(Opart + (size_t)(8192 + row) * 64 + vb);
    *reinterpret_cast<float4*>(out + (size_t)row * 64 + vb) =
        make_float4((w0 * a.x + w1 * c.x) * inv, (w0 * a.y + w1 * c.y) * inv,
                    (w0 * a.z + w1 * c.z) * inv, (w0 * a.w + w1 * c.w) * inv);
}

// ---------------- launch ----------------

extern "C" void kernel_launch(void* const* d_in, const int* in_sizes, int n_in,
                              void* d_out, int out_size, void* d_ws, size_t ws_size,
                              hipStream_t stream)
{
    const float* X  = (const float*)d_in[0];
    const float* Wq = (const float*)d_in[1];
    const float* Wk = (const float*)d_in[2];
    const float* Wv = (const float*)d_in[3];
    float* out = (float*)d_out;

    // workspace layout (shorts). Same 22.4 MB footprint as R1:
    // Opart/ml alias the Xhi/Xlo region (dead after proj_kernel).
    unsigned short* Xhi = (unsigned short*)d_ws;
    unsigned short* Xlo = Xhi + 4194304;   // 2*4096*512
    unsigned short* Whi = Xlo + 4194304;
    unsigned short* Wlo = Whi + 98304;     // 192*512
    unsigned short* Qhi = Wlo + 98304;
    unsigned short* Qlo = Qhi + 524288;    // 8192*64
    unsigned short* Khi = Qlo + 524288;
    unsigned short* Klo = Khi + 524288;
    unsigned short* VT  = Klo + 524288;    // [2][64][4096]
    float* Opart = (float*)Xhi;            // [2][8192][64]  (aliases Xhi/Xlo, 4 MB)
    float* ml    = Opart + 1048576;        // [2][8192][2]   (128 KB, still in Xhi/Xlo)

    split_kernel<<<2048, 256, 0, stream>>>(X, Xhi, Xlo, 1048576);
    splitW_kernel<<<96, 256, 0, stream>>>(Wq, Wk, Wv, Whi, Wlo);
    proj_kernel<<<dim3(256, 3), 64, 0, stream>>>(Xhi, Xlo, Whi, Wlo, Qhi, Qlo, Khi, Klo, VT);
    attn_kernel<<<dim3(256, 2), 512, 0, stream>>>(Qhi, Qlo, Khi, Klo, VT, Opart, ml);
    merge_kernel<<<512, 256, 0, stream>>>(Opart, ml, out);
}

// Round 5
// 90.902 us; speedup vs baseline: 1.0723x; 1.0723x over previous
//
#include <hip/hip_runtime.h>
#include <hip/hip_bf16.h>

// SelfAttention: B=2, S=4096, E=512, D=64, fp32 in/out.
// R5 = R4 (verified) with ZERO arithmetic changes. Perf-only deltas:
//  - attn: __launch_bounds__(512, 2) -> kills VGPR-64 spill storm.
//  - proj: column-group split (grid 256x6, one 32-col MFMA group per block)
//          + __launch_bounds__(64, 1); identical math per output element.

typedef float  f32x16 __attribute__((ext_vector_type(16)));
typedef short  v8bf   __attribute__((ext_vector_type(8)));
typedef int    v4i    __attribute__((ext_vector_type(4)));

#define MFMA32(a, b, c) __builtin_amdgcn_mfma_f32_32x32x16_bf16((a), (b), (c), 0, 0, 0)

union Frag { v4i i4; v8bf b8; unsigned u[4]; };

__device__ __forceinline__ unsigned short f2bf(float x) {  // RNE fp32->bf16
    unsigned u = __float_as_uint(x);
    return (unsigned short)((u + 0x7fffu + ((u >> 16) & 1u)) >> 16);
}
__device__ __forceinline__ float bf2f(unsigned short h) {
    return __uint_as_float(((unsigned)h) << 16);
}
__device__ __forceinline__ unsigned cvt_pk_bf16(float a, float b) {
    unsigned r;
    asm("v_cvt_pk_bf16_f32 %0, %1, %2" : "=v"(r) : "v"(a), "v"(b));
    return r;
}

// ---------------- split kernels: fp32 -> (hi, lo) bf16 ----------------

__global__ __launch_bounds__(256) void split_kernel(
    const float* __restrict__ src, unsigned short* __restrict__ hi,
    unsigned short* __restrict__ lo, int n4)
{
    int i = blockIdx.x * 256 + threadIdx.x;
    const int stride = gridDim.x * 256;
    for (; i < n4; i += stride) {
        float4 v = reinterpret_cast<const float4*>(src)[i];
        unsigned short h0 = f2bf(v.x), h1 = f2bf(v.y), h2 = f2bf(v.z), h3 = f2bf(v.w);
        unsigned short l0 = f2bf(v.x - bf2f(h0)), l1 = f2bf(v.y - bf2f(h1));
        unsigned short l2 = f2bf(v.z - bf2f(h2)), l3 = f2bf(v.w - bf2f(h3));
        reinterpret_cast<uint2*>(hi)[i] =
            make_uint2((unsigned)h0 | ((unsigned)h1 << 16), (unsigned)h2 | ((unsigned)h3 << 16));
        reinterpret_cast<uint2*>(lo)[i] =
            make_uint2((unsigned)l0 | ((unsigned)l1 << 16), (unsigned)l2 | ((unsigned)l3 << 16));
    }
}

// Pack Wq,Wk,Wv (each [64][512]) into W[192][512] hi/lo. 24576 float4s -> 96 blocks.
__global__ __launch_bounds__(256) void splitW_kernel(
    const float* __restrict__ wq, const float* __restrict__ wk, const float* __restrict__ wv,
    unsigned short* __restrict__ hi, unsigned short* __restrict__ lo)
{
    int i = blockIdx.x * 256 + threadIdx.x;  // exactly 24576 threads
    int e = i * 4;
    const float* src = (e < 32768) ? wq : (e < 65536) ? wk : wv;
    int off = e & 32767;
    float4 v = *reinterpret_cast<const float4*>(src + off);
    unsigned short h0 = f2bf(v.x), h1 = f2bf(v.y), h2 = f2bf(v.z), h3 = f2bf(v.w);
    unsigned short l0 = f2bf(v.x - bf2f(h0)), l1 = f2bf(v.y - bf2f(h1));
    unsigned short l2 = f2bf(v.z - bf2f(h2)), l3 = f2bf(v.w - bf2f(h3));
    reinterpret_cast<uint2*>(hi)[i] =
        make_uint2((unsigned)h0 | ((unsigned)h1 << 16), (unsigned)h2 | ((unsigned)h3 << 16));
    reinterpret_cast<uint2*>(lo)[i] =
        make_uint2((unsigned)l0 | ((unsigned)l1 << 16), (unsigned)l2 | ((unsigned)l3 << 16));
}

// ---------------- projection: C[8192][192] = X[8192][512] @ W^T ----------------
// grid = (256 row-tiles, 6 col-groups: {Q,K,V} x {cols 0-31, cols 32-63}),
// 1 wave/block. Same math as R4's a0/a1 pair, one group per block.

__global__ __launch_bounds__(64, 1) void proj_kernel(
    const unsigned short* __restrict__ Xhi, const unsigned short* __restrict__ Xlo,
    const unsigned short* __restrict__ Whi, const unsigned short* __restrict__ Wlo,
    unsigned short* __restrict__ Qhi, unsigned short* __restrict__ Qlo,
    unsigned short* __restrict__ Khi, unsigned short* __restrict__ Klo,
    unsigned short* __restrict__ VT)
{
    __shared__ float t[32][33];
    const int l = threadIdx.x, h = l >> 5, r32 = l & 31;
    const int row0 = blockIdx.x * 32;
    const int g2 = blockIdx.y;   // 0..5
    const int g  = g2 >> 1;      // 0=Q, 1=K, 2=V
    const int ct = g2 & 1;       // 32-column group within the 64 outputs

    f32x16 a0;
#pragma unroll
    for (int r = 0; r < 16; ++r) a0[r] = 0.f;

    for (int kc = 0; kc < 32; ++kc) {
        const int k0 = kc * 16 + 8 * h;
        Frag xh, xl, b0h;
        const int xo = (row0 + r32) * 512 + k0;
        const int w0 = (g * 64 + ct * 32 + r32) * 512 + k0;
        xh.i4  = *reinterpret_cast<const v4i*>(Xhi + xo);
        b0h.i4 = *reinterpret_cast<const v4i*>(Whi + w0);
        a0 = MFMA32(xh.b8, b0h.b8, a0);
        if (g < 2) {  // Q,K need the hi/lo cross terms
            Frag b0l;
            xl.i4  = *reinterpret_cast<const v4i*>(Xlo + xo);
            b0l.i4 = *reinterpret_cast<const v4i*>(Wlo + w0);
            a0 = MFMA32(xh.b8, b0l.b8, a0);
            a0 = MFMA32(xl.b8, b0h.b8, a0);
        }
    }

    if (g == 2) {
        // V: C[row=s][col=v]; store VT[b][v][s] directly
        const int b  = row0 >> 12;
        const int s0 = row0 & 4095;
        const int v = ct * 32 + r32;
#pragma unroll
        for (int u = 0; u < 4; ++u) {
            const int srow = s0 + 8 * u + 4 * h;
            unsigned p0 = (unsigned)f2bf(a0[4 * u])     | ((unsigned)f2bf(a0[4 * u + 1]) << 16);
            unsigned p1 = (unsigned)f2bf(a0[4 * u + 2]) | ((unsigned)f2bf(a0[4 * u + 3]) << 16);
            *reinterpret_cast<uint2*>(VT + (b * 64 + v) * 4096 + srow) = make_uint2(p0, p1);
        }
    } else {
        unsigned short* Oh = g ? Khi : Qhi;
        unsigned short* Ol = g ? Klo : Qlo;
#pragma unroll
        for (int u = 0; u < 16; ++u)
            t[(u & 3) + 8 * (u >> 2) + 4 * h][r32] = a0[u];
        __syncthreads();
        unsigned wh[8], wl[8];
#pragma unroll
        for (int j = 0; j < 8; ++j) {
            float x0 = t[r32][16 * h + 2 * j];
            float x1 = t[r32][16 * h + 2 * j + 1];
            unsigned short h0 = f2bf(x0), h1 = f2bf(x1);
            unsigned short l0 = f2bf(x0 - bf2f(h0)), l1 = f2bf(x1 - bf2f(h1));
            wh[j] = (unsigned)h0 | ((unsigned)h1 << 16);
            wl[j] = (unsigned)l0 | ((unsigned)l1 << 16);
        }
        const int off = (row0 + r32) * 64 + ct * 32 + 16 * h;
        *reinterpret_cast<uint4*>(Oh + off)     = make_uint4(wh[0], wh[1], wh[2], wh[3]);
        *reinterpret_cast<uint4*>(Oh + off + 8) = make_uint4(wh[4], wh[5], wh[6], wh[7]);
        *reinterpret_cast<uint4*>(Ol + off)     = make_uint4(wl[0], wl[1], wl[2], wl[3]);
        *reinterpret_cast<uint4*>(Ol + off + 8) = make_uint4(wl[4], wl[5], wl[6], wl[7]);
    }
}

// ---------------- flash attention (key-split halves) ----------------
// grid (256 q-tiles, 2 key-halves), block 512 (8 waves). Wave w: 256 keys of
// its half (8 iters x 32). Math identical to R4. launch_bounds (512,2) gives
// the register allocator up to 256 VGPRs -> no scratch spills.

__global__ __launch_bounds__(512, 2) void attn_kernel(
    const unsigned short* __restrict__ Qhi, const unsigned short* __restrict__ Qlo,
    const unsigned short* __restrict__ Khi, const unsigned short* __restrict__ Klo,
    const unsigned short* __restrict__ VT,
    float* __restrict__ Opart, float* __restrict__ ml)
{
    __shared__ float sO[8][32][68];
    __shared__ float sm[8][32];
    __shared__ float sl[8][32];

    const int tid = threadIdx.x;
    const int w = tid >> 6;
    const int l = tid & 63;
    const int h = l >> 5;
    const int q = l & 31;
    const int b  = blockIdx.x >> 7;
    const int q0 = (blockIdx.x & 127) * 32;
    const int half = blockIdx.y;

    // Q fragments (B-operand of swapped QK^T): Q[q][d], 4 d-chunks of 16
    Frag qh[4], ql[4];
#pragma unroll
    for (int dc = 0; dc < 4; ++dc) {
        const int o = (b * 4096 + q0 + q) * 64 + dc * 16 + 8 * h;
        qh[dc].i4 = *reinterpret_cast<const v4i*>(Qhi + o);
        ql[dc].i4 = *reinterpret_cast<const v4i*>(Qlo + o);
    }

    f32x16 o0, o1;
#pragma unroll
    for (int r = 0; r < 16; ++r) { o0[r] = 0.f; o1[r] = 0.f; }
    float m_run = -1e30f, l_run = 0.f;

    for (int it = 0; it < 8; ++it) {
        const int key0 = half * 2048 + (it * 8 + w) * 32;
        // --- scores: S[k][q] = sum_d K[k][d] Q[q][d], hi/lo split (3 MFMAs/chunk)
        f32x16 s;
#pragma unroll
        for (int r = 0; r < 16; ++r) s[r] = 0.f;
#pragma unroll
        for (int dc = 0; dc < 4; ++dc) {
            Frag kh, kl;
            const int ko = (b * 4096 + key0 + q) * 64 + dc * 16 + 8 * h;
            kh.i4 = *reinterpret_cast<const v4i*>(Khi + ko);
            kl.i4 = *reinterpret_cast<const v4i*>(Klo + ko);
            s = MFMA32(kh.b8, qh[dc].b8, s);
            s = MFMA32(kh.b8, ql[dc].b8, s);
            s = MFMA32(kl.b8, qh[dc].b8, s);
        }
        // --- online softmax (base 2). Quirk: logits = 8 * score.
        const float cc = 11.541560327111707f;  // 8 * log2(e)
        float s2[16];
        float mb = -1e30f;
#pragma unroll
        for (int r = 0; r < 16; ++r) { s2[r] = s[r] * cc; mb = fmaxf(mb, s2[r]); }
        mb = fmaxf(mb, __shfl_xor(mb, 32));
        const float m_new = fmaxf(m_run, mb);
        const float f = exp2f(m_run - m_new);
        float p[16];
        float ps = 0.f;
#pragma unroll
        for (int r = 0; r < 16; ++r) { p[r] = exp2f(s2[r] - m_new); ps += p[r]; }
        ps += __shfl_xor(ps, 32);
        l_run = l_run * f + ps;
        m_run = m_new;
#pragma unroll
        for (int r = 0; r < 16; ++r) { o0[r] *= f; o1[r] *= f; }

        // --- P (C layout, k = (r&3)+8*(r>>2)+4h) -> bf16 B-frags (k = 16c+8h+j)
        unsigned U[8];
#pragma unroll
        for (int g = 0; g < 4; ++g) {
            U[2 * g]     = cvt_pk_bf16(p[4 * g],     p[4 * g + 1]);
            U[2 * g + 1] = cvt_pk_bf16(p[4 * g + 2], p[4 * g + 3]);
        }
        unsigned t0 = h ? U[0] : U[2];
        unsigned t1 = h ? U[1] : U[3];
        unsigned t2 = h ? U[4] : U[6];
        unsigned t3 = h ? U[5] : U[7];
        unsigned r0 = __shfl_xor(t0, 32);
        unsigned r1 = __shfl_xor(t1, 32);
        unsigned r2 = __shfl_xor(t2, 32);
        unsigned r3 = __shfl_xor(t3, 32);
        Frag p0f, p1f;
        if (h == 0) {
            p0f.u[0] = U[0]; p0f.u[1] = U[1]; p0f.u[2] = r0; p0f.u[3] = r1;
            p1f.u[0] = U[4]; p1f.u[1] = U[5]; p1f.u[2] = r2; p1f.u[3] = r3;
        } else {
            p0f.u[0] = r0; p0f.u[1] = r1; p0f.u[2] = U[2]; p0f.u[3] = U[3];
            p1f.u[0] = r2; p1f.u[1] = r3; p1f.u[2] = U[6]; p1f.u[3] = U[7];
        }
        // --- PV: O^T[v][q] += V^T[v][k] P[k][q]
#pragma unroll
        for (int c = 0; c < 2; ++c) {
            const Frag& pf = c ? p1f : p0f;
#pragma unroll
            for (int vc = 0; vc < 2; ++vc) {
                Frag vf;
                const int vo = (b * 64 + vc * 32 + q) * 4096 + key0 + c * 16 + 8 * h;
                vf.i4 = *reinterpret_cast<const v4i*>(VT + vo);
                if (vc == 0) o0 = MFMA32(vf.b8, pf.b8, o0);
                else         o1 = MFMA32(vf.b8, pf.b8, o1);
            }
        }
    }

    // --- merge the 8 per-wave partials -> per-block partial (m*, L, unnorm O)
    if (h == 0) { sm[w][q] = m_run; sl[w][q] = l_run; }
#pragma unroll
    for (int vc = 0; vc < 2; ++vc) {
        const f32x16& a = vc ? o1 : o0;
#pragma unroll
        for (int u = 0; u < 4; ++u) {
            float4 v4 = make_float4(a[4 * u], a[4 * u + 1], a[4 * u + 2], a[4 * u + 3]);
            *reinterpret_cast<float4*>(&sO[w][q][vc * 32 + 8 * u + 4 * h]) = v4;
        }
    }
    __syncthreads();

    const int qq = tid >> 4;
    const int vb = (tid & 15) * 4;
    float mstar = sm[0][qq];
#pragma unroll
    for (int ww = 1; ww < 8; ++ww) mstar = fmaxf(mstar, sm[ww][qq]);
    float L = 0.f, acc0 = 0.f, acc1 = 0.f, acc2 = 0.f, acc3 = 0.f;
#pragma unroll
    for (int ww = 0; ww < 8; ++ww) {
        const float fw = exp2f(sm[ww][qq] - mstar);
        L += fw * sl[ww][qq];
        acc0 += fw * sO[ww][qq][vb + 0];
        acc1 += fw * sO[ww][qq][vb + 1];
        acc2 += fw * sO[ww][qq][vb + 2];
        acc3 += fw * sO[ww][qq][vb + 3];
    }
    const int row = b * 4096 + q0 + qq;
    *reinterpret_cast<float4*>(Opart + ((size_t)half * 8192 + row) * 64 + vb) =
        make_float4(acc0, acc1, acc2, acc3);
    if (vb == 0) {
        ml[((size_t)half * 8192 + row) * 2 + 0] = mstar;
        ml[((size_t)half * 8192 + row) * 2 + 1] = L;
    }
}

// ---------------- cross-block merge of the 2 key-halves ----------------
__global__ __launch_bounds__(256) void merge_kernel(
    const float* __restrict__ Opart, const float* __restrict__ ml, float* __restrict__ out)
{
    const int idx = blockIdx.x * 256 + threadIdx.x;  // 131072
    const int row = idx >> 4, vb = (idx & 15) * 4;
    const float m0 = ml[row * 2 + 0],            l0 = ml[row * 2 + 1];
    const float m1 = ml[(8192 + row) * 2 + 0],   l1 = ml[(8192 + row) * 2 + 1];
    const float ms = fmaxf(m0, m1);
    const float w0 = exp2f(m0 - ms), w1 = exp2f(m1 - ms);
    const float inv = 1.0f / (w0 * l0 + w1 * l1);
    float4 a = *reinterpret_cast<const float4*>(Opart + (size_t)row * 64 + vb);
    float4 c = *reinterpret_cast<const float4*>(Opart + (size_t)(8192 + row) * 64 + vb);
    *reinterpret_cast<float4*>(out + (size_t)row * 64 + vb) =
        make_float4((w0 * a.x + w1 * c.x) * inv, (w0 * a.y + w1 * c.y) * inv,
                    (w0 * a.z + w1 * c.z) * inv, (w0 * a.w + w1 * c.w) * inv);
}

// ---------------- launch ----------------

extern "C" void kernel_launch(void* const* d_in, const int* in_sizes, int n_in,
                              void* d_out, int out_size, void* d_ws, size_t ws_size,
                              hipStream_t stream)
{
    const float* X  = (const float*)d_in[0];
    const float* Wq = (const float*)d_in[1];
    const float* Wk = (const float*)d_in[2];
    const float* Wv = (const float*)d_in[3];
    float* out = (float*)d_out;

    // workspace layout (shorts). Opart/ml alias Xhi/Xlo (dead after proj).
    unsigned short* Xhi = (unsigned short*)d_ws;
    unsigned short* Xlo = Xhi + 4194304;   // 2*4096*512
    unsigned short* Whi = Xlo + 4194304;
    unsigned short* Wlo = Whi + 98304;     // 192*512
    unsigned short* Qhi = Wlo + 98304;
    unsigned short* Qlo = Qhi + 524288;    // 8192*64
    unsigned short* Khi = Qlo + 524288;
    unsigned short* Klo = Khi + 524288;
    unsigned short* VT  = Klo + 524288;    // [2][64][4096]
    float* Opart = (float*)Xhi;            // [2][8192][64]  (aliases Xhi/Xlo, 4 MB)
    float* ml    = Opart + 1048576;        // [2][8192][2]   (128 KB, still in Xhi/Xlo)

    split_kernel<<<2048, 256, 0, stream>>>(X, Xhi, Xlo, 1048576);
    splitW_kernel<<<96, 256, 0, stream>>>(Wq, Wk, Wv, Whi, Wlo);
    proj_kernel<<<dim3(256, 6), 64, 0, stream>>>(Xhi, Xlo, Whi, Wlo, Qhi, Qlo, Khi, Klo, VT);
    attn_kernel<<<dim3(256, 2), 512, 0, stream>>>(Qhi, Qlo, Khi, Klo, VT, Opart, ml);
    merge_kernel<<<512, 256, 0, stream>>>(Opart, ml, out);
}